// Round 4
// baseline (638.220 us; speedup 1.0000x reference)
//
#include <hip/hip_runtime.h>
#include <hip/hip_bf16.h>

#define N_TOK 8192
#define DDIM 1024
#define HDIM 4096
#define NEXP 8
#define TOPK 2
#define NK (N_TOK*TOPK)
#define BM 256
#define BK 64
#define MAXT 72    // 16384/256 + 8 pad tiles

typedef __hip_bfloat16 bf16;
typedef __attribute__((ext_vector_type(8))) short bf16x8;
typedef __attribute__((ext_vector_type(4))) float f32x4;

__device__ __forceinline__ void gload16(const void* g, void* lds) {
  auto l = (__attribute__((address_space(3))) unsigned int*)(unsigned int)(unsigned long long)lds;
  auto gg = (const __attribute__((address_space(1))) unsigned int*)(unsigned long long)g;
  __builtin_amdgcn_global_load_lds(gg, l, 16, 0, 0);
}

// ---- router ----
__global__ void k_detect(const int* __restrict__ idx, int* __restrict__ flag) {
  if (threadIdx.x == 0 && blockIdx.x == 0) {
    int allz = 1;
    for (int i = 1; i < 32; i += 2) allz &= (idx[i] == 0);
    *flag = allz ? 2 : 1;   // 2 => int64 little-endian, 1 => int32
  }
}

__global__ void k_count(const int* __restrict__ idx, const int* __restrict__ flag,
                        int* __restrict__ cnt) {
  int r = blockIdx.x * blockDim.x + threadIdx.x;
  if (r >= NK) return;
  int s = *flag;
  int e = idx[r * s];
  e = min(max(e, 0), NEXP - 1);
  atomicAdd(&cnt[e], 1);
}

__global__ void k_scan(const int* __restrict__ cnt, int* __restrict__ offp,
                       int* __restrict__ off2, int* __restrict__ texp,
                       int* __restrict__ tok) {
  __shared__ int so[NEXP + 1], sc[NEXP];
  int tid = threadIdx.x;
  if (tid == 0) {
    int cum = 0;
    for (int e = 0; e < NEXP; e++) {
      so[e] = cum; sc[e] = cnt[e];
      cum += ((cnt[e] + BM - 1) / BM) * BM;
    }
    so[NEXP] = cum;
    for (int e = 0; e <= NEXP; e++) offp[e] = so[e];
  }
  __syncthreads();
  if (tid < NEXP) off2[tid] = so[tid];
  int total_tiles = so[NEXP] / BM;
  for (int t = tid; t < MAXT; t += blockDim.x) {
    int e = -1;
    if (t < total_tiles) {
      for (int q = 0; q < NEXP; q++)
        if (t * BM >= so[q] && t * BM < so[q + 1]) e = q;
    }
    texp[t] = e;
  }
  for (int e = 0; e < NEXP; e++) {
    int start = so[e] + sc[e], end = so[e + 1];
    for (int i = start + tid; i < end; i += blockDim.x) tok[i] = 0;
  }
}

__global__ void k_scatter(const int* __restrict__ idx, const int* __restrict__ flag,
                          int* __restrict__ off2, int* __restrict__ tok,
                          int* __restrict__ pos) {
  int r = blockIdx.x * blockDim.x + threadIdx.x;
  if (r >= NK) return;
  int s = *flag;
  int e = idx[r * s];
  e = min(max(e, 0), NEXP - 1);
  int p = atomicAdd(&off2[e], 1);
  tok[p] = r >> 1;
  pos[r] = p;
}

// ---- converts ----
__global__ void k_cvt_x(const float* __restrict__ x, bf16* __restrict__ xb) {
  int i = blockIdx.x * blockDim.x + threadIdx.x;   // over N*D/8
  if (i >= N_TOK * DDIM / 8) return;
  float4 a = ((const float4*)x)[(size_t)i * 2];
  float4 b = ((const float4*)x)[(size_t)i * 2 + 1];
  union { bf16 h[8]; uint4 v; } u;
  u.h[0] = __float2bfloat16(a.x); u.h[1] = __float2bfloat16(a.y);
  u.h[2] = __float2bfloat16(a.z); u.h[3] = __float2bfloat16(a.w);
  u.h[4] = __float2bfloat16(b.x); u.h[5] = __float2bfloat16(b.y);
  u.h[6] = __float2bfloat16(b.z); u.h[7] = __float2bfloat16(b.w);
  *(uint4*)&xb[(size_t)i * 8] = u.v;
}

// [E][R][C] fp32 -> [E][C][R] bf16, ushort2 stores
__global__ void k_transpose(const float* __restrict__ in, bf16* __restrict__ out,
                            int R, int C) {
  __shared__ float t[32][33];
  size_t ebase = (size_t)blockIdx.z * R * C;
  int tx = threadIdx.x & 31, ty = threadIdx.x >> 5;
  int c0 = blockIdx.x * 32, r0 = blockIdx.y * 32;
#pragma unroll
  for (int j = 0; j < 4; j++)
    t[ty + j * 8][tx] = in[ebase + (size_t)(r0 + ty + j * 8) * C + c0 + tx];
  __syncthreads();
  int tx2 = (threadIdx.x & 15) * 2;
  int cy  = threadIdx.x >> 4;
#pragma unroll
  for (int p = 0; p < 2; p++) {
    int c = cy + p * 16;
    union { bf16 h[2]; unsigned int u; } w;
    w.h[0] = __float2bfloat16(t[tx2][c]);
    w.h[1] = __float2bfloat16(t[tx2 + 1][c]);
    *(unsigned int*)&out[ebase + (size_t)(c0 + c) * R + r0 + tx2] = w.u;
  }
}

// ---- grouped GEMM: 256x256x64, 8 waves (2Mx4N), wave tile 128x64 ----
// Per K-tile: 4 phases {reads@top || stage-issue -> bar -> lgkm0 -> MFMA -> bar},
// all B reads in phase 0, vmcnt(4) at phase-3 tail (m201 discipline).
// MODE 0: X(gathered) @ W1t -> hbuf bf16 (+bias, ReLU).
// MODE 1: hbuf @ W2t -> ybuf bf16 (+bias).
template<int MODE>
__global__ __launch_bounds__(512, 2) void k_gemm(
    const bf16* __restrict__ A, const bf16* __restrict__ Bt,
    const float* __restrict__ bias, const int* __restrict__ texp,
    const int* __restrict__ tok, int tile_base, void* __restrict__ Cout)
{
  constexpr int KT    = MODE ? HDIM : DDIM;
  constexpr int NCOL  = MODE ? DDIM : HDIM;
  constexpr int GX    = NCOL / 256;          // 16 or 4
  constexpr int NT    = KT / BK;             // 16 or 64
  constexpr int BUFE  = 512 * BK;            // elems per LDS buffer (A 256 + B 256 rows)
  constexpr int HALF_E = 128 * BK;

  // bijective XCD-aware swizzle (m204)
  int nwg = gridDim.x, orig = blockIdx.x;
  int q8 = nwg >> 3, r8 = nwg & 7;
  int xcd = orig & 7, jj0 = orig >> 3;
  int w = (xcd < r8 ? xcd * (q8 + 1) : r8 * (q8 + 1) + (xcd - r8) * q8) + jj0;
  int tn = w % GX;
  int tm = tile_base + w / GX;
  int e = texp[tm];
  if (e < 0) return;

  int tid = threadIdx.x, lane = tid & 63, wid = tid >> 6;
  int wm = wid >> 2, wn = wid & 3;           // 2M x 4N
  int lr = lane & 15, kg = lane >> 4;

  __shared__ __align__(16) bf16 lds[2 * BUFE];   // 128 KiB

  const bf16* Bexp = Bt + ((size_t)e * NCOL + (size_t)tn * 256) * KT;

  // hoisted staging pointers (source-side swizzle, rule #21)
  const bf16* aptr[2][2];
  const bf16* bptr[2][2];
#pragma unroll
  for (int h = 0; h < 2; ++h) {
#pragma unroll
    for (int it = 0; it < 2; ++it) {
      int ch = it * 512 + tid, il = ch >> 3, c = ch & 7;
      int row = h * 128 + il;
      int arow = MODE ? (tm - tile_base) * BM + row : tok[tm * BM + row];
      aptr[h][it] = A + (size_t)arow * KT + (c ^ (il & 7)) * 8;
      bptr[h][it] = Bexp + (size_t)row * KT + (c ^ (il & 7)) * 8;
    }
  }

  auto stageA = [&](int h, int kt) {
    if (kt >= NT) return;
    char* dst = (char*)lds + ((size_t)(kt & 1) * BUFE + h * HALF_E) * 2;
#pragma unroll
    for (int it = 0; it < 2; ++it)
      gload16(aptr[h][it] + kt * BK, dst + (it * 512 + wid * 64) * 16);
  };
  auto stageB = [&](int h, int kt) {
    if (kt >= NT) return;
    char* dst = (char*)lds + ((size_t)(kt & 1) * BUFE + BM * BK + h * HALF_E) * 2;
#pragma unroll
    for (int it = 0; it < 2; ++it)
      gload16(bptr[h][it] + kt * BK, dst + (it * 512 + wid * 64) * 16);
  };

  f32x4 acc[8][4];
#pragma unroll
  for (int i = 0; i < 8; i++)
#pragma unroll
    for (int j = 0; j < 4; j++) acc[i][j] = (f32x4){0.f, 0.f, 0.f, 0.f};

  bf16x8 bv[8];
  auto readB = [&](const bf16* buf) {
    const bf16* base = buf + BM * BK;
#pragma unroll
    for (int ni = 0; ni < 4; ++ni)
#pragma unroll
      for (int kh = 0; kh < 2; ++kh) {
        int n = wn * 64 + ni * 16 + lr;
        int ph = (kh * 4 + kg) ^ (n & 7);
        bv[ni * 2 + kh] = *(const bf16x8*)&base[n * BK + ph * 8];
      }
  };
  auto readA = [&](const bf16* buf, int q, bf16x8* av) {
#pragma unroll
    for (int g = 0; g < 2; ++g)
#pragma unroll
      for (int kh = 0; kh < 2; ++kh) {
        int m = wm * 128 + (q * 2 + g) * 16 + lr;
        int ph = (kh * 4 + kg) ^ (m & 7);
        av[g * 2 + kh] = *(const bf16x8*)&buf[m * BK + ph * 8];
      }
  };
  auto domfma = [&](int q, bf16x8* av) {
    __builtin_amdgcn_s_setprio(1);
#pragma unroll
    for (int g = 0; g < 2; ++g)
#pragma unroll
      for (int ni = 0; ni < 4; ++ni)
#pragma unroll
        for (int kh = 0; kh < 2; ++kh)
          acc[q * 2 + g][ni] = __builtin_amdgcn_mfma_f32_16x16x32_bf16(
              av[g * 2 + kh], bv[ni * 2 + kh], acc[q * 2 + g][ni], 0, 0, 0);
    __builtin_amdgcn_s_setprio(0);
  };

#define LGKM0() do { asm volatile("s_waitcnt lgkmcnt(0)" ::: "memory"); \
                     __builtin_amdgcn_sched_barrier(0); } while(0)

  // prologue: B(0), A(0), B(1); publish tile 0
  stageB(0, 0); stageB(1, 0); stageA(0, 0); stageA(1, 0); stageB(0, 1); stageB(1, 1);
  asm volatile("s_waitcnt vmcnt(4)" ::: "memory");   // retire B(0), A(0)
  __builtin_amdgcn_s_barrier();

#pragma unroll 1
  for (int t = 0; t < NT; ++t) {
    const bf16* buf = lds + (t & 1) * BUFE;
    bf16x8 av[4];

    // phase 0: all B-frags + A q0 at top, overlap stage issue
    readB(buf);
    readA(buf, 0, av);
    stageA(0, t + 1);
    asm volatile("s_waitcnt lgkmcnt(8)" ::: "memory");  // smooth the 12-read burst
    __builtin_amdgcn_s_barrier();
    LGKM0();
    domfma(0, av);
    __builtin_amdgcn_s_barrier();

    // phase 1
    readA(buf, 1, av);
    stageA(1, t + 1);
    __builtin_amdgcn_s_barrier();
    LGKM0();
    domfma(1, av);
    __builtin_amdgcn_s_barrier();

    // phase 2
    readA(buf, 2, av);
    stageB(0, t + 2);
    __builtin_amdgcn_s_barrier();
    LGKM0();
    domfma(2, av);
    __builtin_amdgcn_s_barrier();

    // phase 3 (tail): stage, counted vmcnt publishes tile t+1
    readA(buf, 3, av);
    stageB(1, t + 2);
    if (t < NT - 2)       asm volatile("s_waitcnt vmcnt(4)" ::: "memory");
    else if (t == NT - 2) asm volatile("s_waitcnt vmcnt(0)" ::: "memory");
    __builtin_amdgcn_s_barrier();
    LGKM0();
    domfma(3, av);
    __builtin_amdgcn_s_barrier();
  }

  // epilogue
  const float* be = bias + (size_t)e * NCOL;
#pragma unroll
  for (int ni = 0; ni < 4; ++ni) {
    int n = tn * 256 + wn * 64 + ni * 16 + lr;
    float bvv = be[n];
#pragma unroll
    for (int mi = 0; mi < 8; ++mi) {
#pragma unroll
      for (int j = 0; j < 4; j++) {
        int mrow = wm * 128 + mi * 16 + kg * 4 + j;   // C/D map m89
        float v = acc[mi][ni][j] + bvv;
        if (MODE == 0) {
          v = fmaxf(v, 0.f);
          ((bf16*)Cout)[(size_t)((tm - tile_base) * BM + mrow) * NCOL + n] =
              __float2bfloat16(v);
        } else {
          ((bf16*)Cout)[(size_t)(tm * BM + mrow) * NCOL + n] = __float2bfloat16(v);
        }
      }
    }
  }
#undef LGKM0
}

// ---- combine (bf16 y) ----
__global__ void k_combine(const bf16* __restrict__ y, const float* __restrict__ prob,
                          const int* __restrict__ pos, float* __restrict__ out) {
  int gid = blockIdx.x * blockDim.x + threadIdx.x;  // over N*D/8
  if (gid >= N_TOK * DDIM / 8) return;
  int n = gid >> 7;          // DDIM/8 = 128
  int d8 = gid & 127;
  int r0 = pos[2 * n], r1 = pos[2 * n + 1];
  float p0 = prob[2 * n], p1 = prob[2 * n + 1];
  uint4 a = *(const uint4*)&y[(size_t)r0 * DDIM + d8 * 8];
  uint4 b = *(const uint4*)&y[(size_t)r1 * DDIM + d8 * 8];
  const unsigned short* ah = (const unsigned short*)&a;
  const unsigned short* bh = (const unsigned short*)&b;
  float o[8];
#pragma unroll
  for (int k = 0; k < 8; k++) {
    float fa = __uint_as_float((unsigned)ah[k] << 16);
    float fb = __uint_as_float((unsigned)bh[k] << 16);
    o[k] = p0 * fa + p1 * fb;
  }
  float4* op = (float4*)&out[(size_t)n * DDIM + d8 * 8];
  op[0] = (float4){o[0], o[1], o[2], o[3]};
  op[1] = (float4){o[4], o[5], o[6], o[7]};
  if (gid == 0) out[(size_t)N_TOK * DDIM] = 0.f;   // total_loss
}

extern "C" void kernel_launch(void* const* d_in, const int* in_sizes, int n_in,
                              void* d_out, int out_size, void* d_ws, size_t ws_size,
                              hipStream_t stream) {
  const float* x    = (const float*)d_in[0];
  const float* prob = (const float*)d_in[1];
  const int*   idx  = (const int*)d_in[2];
  const float* W1   = (const float*)d_in[3];
  const float* b1   = (const float*)d_in[4];
  const float* W2   = (const float*)d_in[5];
  const float* b2   = (const float*)d_in[6];
  float* out = (float*)d_out;

  char* ws = (char*)d_ws;
  size_t cur = 0;
  auto alloc = [&](size_t bytes) -> void* {
    cur = (cur + 255) & ~(size_t)255;
    void* p = ws + cur; cur += bytes; return p;
  };
  int* cnt   = (int*)alloc(NEXP * 4);
  int* offp  = (int*)alloc((NEXP + 1) * 4);
  int* off2  = (int*)alloc(NEXP * 4);
  int* flag  = (int*)alloc(4);
  int* texp  = (int*)alloc(MAXT * 4);
  int* tok   = (int*)alloc((size_t)MAXT * BM * 4);
  int* pos   = (int*)alloc((size_t)NK * 4);
  bf16* Xb   = (bf16*)alloc((size_t)N_TOK * DDIM * 2);
  bf16* W1t  = (bf16*)alloc((size_t)NEXP * HDIM * DDIM * 2);
  bf16* W2t  = (bf16*)alloc((size_t)NEXP * DDIM * HDIM * 2);
  bf16* ybuf = (bf16*)alloc((size_t)MAXT * BM * DDIM * 2);
  cur = (cur + 255) & ~(size_t)255;
  size_t h_off = cur;
  size_t h_avail = ws_size > h_off ? ws_size - h_off : 0;
  long long ts_ll = (long long)(h_avail / ((size_t)BM * HDIM * 2));
  int ts = (int)(ts_ll < 1 ? 1 : (ts_ll > MAXT ? MAXT : ts_ll));
  bf16* hbuf = (bf16*)(ws + h_off);

  hipMemsetAsync(cnt, 0, NEXP * 4, stream);
  k_detect<<<1, 64, 0, stream>>>(idx, flag);
  k_count<<<(NK + 255) / 256, 256, 0, stream>>>(idx, flag, cnt);
  k_scan<<<1, 256, 0, stream>>>(cnt, offp, off2, texp, tok);
  k_scatter<<<(NK + 255) / 256, 256, 0, stream>>>(idx, flag, off2, tok, pos);
  k_cvt_x<<<(N_TOK * DDIM / 8 + 255) / 256, 256, 0, stream>>>(x, Xb);
  k_transpose<<<dim3(HDIM / 32, DDIM / 32, NEXP), 256, 0, stream>>>(W1, W1t, DDIM, HDIM);
  k_transpose<<<dim3(DDIM / 32, HDIM / 32, NEXP), 256, 0, stream>>>(W2, W2t, HDIM, DDIM);

  for (int base = 0; base < MAXT; base += ts) {
    int cnt_t = (MAXT - base < ts) ? (MAXT - base) : ts;
    k_gemm<0><<<dim3((HDIM / 256) * cnt_t), 512, 0, stream>>>(
        Xb, W1t, b1, texp, tok, base, (void*)hbuf);
    k_gemm<1><<<dim3((DDIM / 256) * cnt_t), 512, 0, stream>>>(
        hbuf, W2t, b2, texp, tok, base, (void*)ybuf);
  }
  k_combine<<<(N_TOK * DDIM / 8 + 255) / 256, 256, 0, stream>>>(ybuf, prob, pos, out);
}

// Round 5
// 637.700 us; speedup vs baseline: 1.0008x; 1.0008x over previous
//
#include <hip/hip_runtime.h>
#include <hip/hip_bf16.h>

#define N_TOK 8192
#define DDIM 1024
#define HDIM 4096
#define NEXP 8
#define TOPK 2
#define NK (N_TOK*TOPK)
#define BM 256
#define BK 64
#define MAXT 72    // 16384/256 + 8 pad tiles

typedef __hip_bfloat16 bf16;
typedef __attribute__((ext_vector_type(8))) short bf16x8;
typedef __attribute__((ext_vector_type(4))) float f32x4;

__device__ __forceinline__ void gload16(const void* g, void* lds) {
  auto l = (__attribute__((address_space(3))) unsigned int*)(unsigned int)(unsigned long long)lds;
  auto gg = (const __attribute__((address_space(1))) unsigned int*)(unsigned long long)g;
  __builtin_amdgcn_global_load_lds(gg, l, 16, 0, 0);
}

// ---- router ----
__global__ void k_detect(const int* __restrict__ idx, int* __restrict__ flag) {
  if (threadIdx.x == 0 && blockIdx.x == 0) {
    int allz = 1;
    for (int i = 1; i < 32; i += 2) allz &= (idx[i] == 0);
    *flag = allz ? 2 : 1;   // 2 => int64 little-endian, 1 => int32
  }
}

__global__ void k_count(const int* __restrict__ idx, const int* __restrict__ flag,
                        int* __restrict__ cnt) {
  int r = blockIdx.x * blockDim.x + threadIdx.x;
  if (r >= NK) return;
  int s = *flag;
  int e = idx[r * s];
  e = min(max(e, 0), NEXP - 1);
  atomicAdd(&cnt[e], 1);
}

__global__ void k_scan(const int* __restrict__ cnt, int* __restrict__ offp,
                       int* __restrict__ off2, int* __restrict__ texp,
                       int* __restrict__ tok) {
  __shared__ int so[NEXP + 1], sc[NEXP];
  int tid = threadIdx.x;
  if (tid == 0) {
    int cum = 0;
    for (int e = 0; e < NEXP; e++) {
      so[e] = cum; sc[e] = cnt[e];
      cum += ((cnt[e] + BM - 1) / BM) * BM;
    }
    so[NEXP] = cum;
    for (int e = 0; e <= NEXP; e++) offp[e] = so[e];
  }
  __syncthreads();
  if (tid < NEXP) off2[tid] = so[tid];
  int total_tiles = so[NEXP] / BM;
  for (int t = tid; t < MAXT; t += blockDim.x) {
    int e = -1;
    if (t < total_tiles) {
      for (int q = 0; q < NEXP; q++)
        if (t * BM >= so[q] && t * BM < so[q + 1]) e = q;
    }
    texp[t] = e;
  }
  for (int e = 0; e < NEXP; e++) {
    int start = so[e] + sc[e], end = so[e + 1];
    for (int i = start + tid; i < end; i += blockDim.x) tok[i] = 0;
  }
}

__global__ void k_scatter(const int* __restrict__ idx, const int* __restrict__ flag,
                          int* __restrict__ off2, int* __restrict__ tok,
                          int* __restrict__ pos) {
  int r = blockIdx.x * blockDim.x + threadIdx.x;
  if (r >= NK) return;
  int s = *flag;
  int e = idx[r * s];
  e = min(max(e, 0), NEXP - 1);
  int p = atomicAdd(&off2[e], 1);
  tok[p] = r >> 1;
  pos[r] = p;
}

// ---- gather + fp32->bf16: Xg[p][:] = bf16(x[tok[p]][:]) ----
__global__ void k_gather(const float* __restrict__ x, const int* __restrict__ tok,
                         const int* __restrict__ offp, bf16* __restrict__ xg) {
  int rows = offp[NEXP];
  int chunks = rows * (DDIM / 8);
  int stride = gridDim.x * blockDim.x;
  for (int i = blockIdx.x * blockDim.x + threadIdx.x; i < chunks; i += stride) {
    int p = i >> 7;            // DDIM/8 = 128
    int c = i & 127;
    int r = tok[p];
    float4 a = ((const float4*)x)[((size_t)r * DDIM + c * 8) / 4];
    float4 b = ((const float4*)x)[((size_t)r * DDIM + c * 8) / 4 + 1];
    union { bf16 h[8]; uint4 v; } u;
    u.h[0] = __float2bfloat16(a.x); u.h[1] = __float2bfloat16(a.y);
    u.h[2] = __float2bfloat16(a.z); u.h[3] = __float2bfloat16(a.w);
    u.h[4] = __float2bfloat16(b.x); u.h[5] = __float2bfloat16(b.y);
    u.h[6] = __float2bfloat16(b.z); u.h[7] = __float2bfloat16(b.w);
    *(uint4*)&xg[(size_t)p * DDIM + c * 8] = u.v;
  }
}

// [E][R][C] fp32 -> [E][C][R] bf16, ushort2 stores
__global__ void k_transpose(const float* __restrict__ in, bf16* __restrict__ out,
                            int R, int C) {
  __shared__ float t[32][33];
  size_t ebase = (size_t)blockIdx.z * R * C;
  int tx = threadIdx.x & 31, ty = threadIdx.x >> 5;
  int c0 = blockIdx.x * 32, r0 = blockIdx.y * 32;
#pragma unroll
  for (int j = 0; j < 4; j++)
    t[ty + j * 8][tx] = in[ebase + (size_t)(r0 + ty + j * 8) * C + c0 + tx];
  __syncthreads();
  int tx2 = (threadIdx.x & 15) * 2;
  int cy  = threadIdx.x >> 4;
#pragma unroll
  for (int p = 0; p < 2; p++) {
    int c = cy + p * 16;
    union { bf16 h[2]; unsigned int u; } w;
    w.h[0] = __float2bfloat16(t[tx2][c]);
    w.h[1] = __float2bfloat16(t[tx2 + 1][c]);
    *(unsigned int*)&out[ebase + (size_t)(c0 + c) * R + r0 + tx2] = w.u;
  }
}

// ---- persistent grouped GEMM: 256x256x64 tiles, 8 waves, seamless pipeline ----
// MODE 0: Xg(dense-gathered) @ W1t -> hbuf bf16 (+bias, ReLU), slice-local C rows.
// MODE 1: hbuf @ W2t -> ybuf bf16 (+bias), global C rows.
template<int MODE>
__global__ __launch_bounds__(512, 2) void k_gemm(
    const bf16* __restrict__ A, const bf16* __restrict__ Bt,
    const float* __restrict__ bias, const int* __restrict__ texp,
    const int* __restrict__ offp, int tile_base, int tile_cnt,
    void* __restrict__ Cout)
{
  constexpr int KT   = MODE ? HDIM : DDIM;
  constexpr int NCOL = MODE ? DDIM : HDIM;
  constexpr int GX   = NCOL / 256;           // 16 or 4
  constexpr int LGXc = MODE ? 2 : 4;
  constexpr int NT   = KT / BK;              // 64 or 16
  constexpr int BUFE = 512 * BK;
  constexpr int HALF_E = 128 * BK;

  int total = offp[NEXP] / BM;
  int tmEnd = tile_base + tile_cnt; if (tmEnd > total) tmEnd = total;
  int nW = (tmEnd - tile_base) * GX;
  int tid = threadIdx.x, lane = tid & 63, wid = tid >> 6;
  int wm = wid >> 2, wn = wid & 3;           // 2M x 4N
  int lr = lane & 15, kg = lane >> 4;
  int GDX = gridDim.x;

  int w0 = blockIdx.x;
  if (w0 >= nW) return;

  __shared__ __align__(16) bf16 lds[2 * BUFE];   // 128 KiB
  __shared__ int texpLds[MAXT];

  for (int i = tid; i < MAXT; i += 512) texpLds[i] = texp[i];
  __syncthreads();

  // per-tile state: 32-bit element offsets for half-0 (h1 = +128*KT)
  unsigned aoC[2], boC[2], aoN[2], boN[2];
  int eC, tmC, tmrC, eN, tmN, tmrN;

  auto prep = [&](int wi, unsigned* ao, unsigned* bo, int& e, int& tm, int& tmr) {
    int tn = wi & (GX - 1);
    tmr = wi >> LGXc;
    tm = tile_base + tmr;
    e = texpLds[tm];
    int arb = (MODE ? tmr : tm) * BM;
#pragma unroll
    for (int it = 0; it < 2; ++it) {
      int ch = it * 512 + tid, il = ch >> 3, c = ch & 7;
      int cs = (c ^ (il & 7)) * 8;
      ao[it] = (unsigned)((arb + il) * KT + cs);
      bo[it] = (unsigned)((e * NCOL + tn * 256 + il) * KT + cs);
    }
  };

  auto stA = [&](const unsigned* ao, int h, int kt, int par) {
    char* dst = (char*)lds + ((size_t)par * BUFE + h * HALF_E) * 2;
#pragma unroll
    for (int it = 0; it < 2; ++it)
      gload16(A + ao[it] + h * (128 * KT) + kt * BK, dst + (it * 512 + wid * 64) * 16);
  };
  auto stB = [&](const unsigned* bo, int h, int kt, int par) {
    char* dst = (char*)lds + ((size_t)par * BUFE + BM * BK + h * HALF_E) * 2;
#pragma unroll
    for (int it = 0; it < 2; ++it)
      gload16(Bt + bo[it] + h * (128 * KT) + kt * BK, dst + (it * 512 + wid * 64) * 16);
  };

  f32x4 acc[8][4];
  bf16x8 bv[8];
  auto readB = [&](const bf16* buf) {
    const bf16* base = buf + BM * BK;
#pragma unroll
    for (int ni = 0; ni < 4; ++ni)
#pragma unroll
      for (int kh = 0; kh < 2; ++kh) {
        int n = wn * 64 + ni * 16 + lr;
        int ph = (kh * 4 + kg) ^ (n & 7);
        bv[ni * 2 + kh] = *(const bf16x8*)&base[n * BK + ph * 8];
      }
  };
  auto readA = [&](const bf16* buf, int q, bf16x8* av) {
#pragma unroll
    for (int g = 0; g < 2; ++g)
#pragma unroll
      for (int kh = 0; kh < 2; ++kh) {
        int m = wm * 128 + (q * 2 + g) * 16 + lr;
        int ph = (kh * 4 + kg) ^ (m & 7);
        av[g * 2 + kh] = *(const bf16x8*)&buf[m * BK + ph * 8];
      }
  };
  auto domfma = [&](int q, bf16x8* av) {
    __builtin_amdgcn_s_setprio(1);
#pragma unroll
    for (int g = 0; g < 2; ++g)
#pragma unroll
      for (int ni = 0; ni < 4; ++ni)
#pragma unroll
        for (int kh = 0; kh < 2; ++kh)
          acc[q * 2 + g][ni] = __builtin_amdgcn_mfma_f32_16x16x32_bf16(
              av[g * 2 + kh], bv[ni * 2 + kh], acc[q * 2 + g][ni], 0, 0, 0);
    __builtin_amdgcn_s_setprio(0);
  };

#define LGKM0() do { asm volatile("s_waitcnt lgkmcnt(0)" ::: "memory"); \
                     __builtin_amdgcn_sched_barrier(0); } while(0)

  int wi = w0;
  bool hasN = (wi + GDX) < nW;
  prep(wi, aoC, boC, eC, tmC, tmrC);
  if (hasN) prep(wi + GDX, aoN, boN, eN, tmN, tmrN);

  // prologue: B(0), A(0) -> par0; B(1) -> par1
  stB(boC, 0, 0, 0); stB(boC, 1, 0, 0);
  stA(aoC, 0, 0, 0); stA(aoC, 1, 0, 0);
  stB(boC, 0, 1, 1); stB(boC, 1, 1, 1);
  asm volatile("s_waitcnt vmcnt(4)" ::: "memory");   // publish tile 0 k-tile 0
  __builtin_amdgcn_s_barrier();

  while (true) {
#pragma unroll
    for (int i = 0; i < 8; i++)
#pragma unroll
      for (int j = 0; j < 4; j++) acc[i][j] = (f32x4){0.f, 0.f, 0.f, 0.f};

#pragma unroll 1
    for (int kt = 0; kt < NT; ++kt) {
      int par = kt & 1, parN = par ^ 1;
      const bf16* buf = lds + par * BUFE;
      bf16x8 av[4];

      // phase 0
      readB(buf);
      readA(buf, 0, av);
      if (kt < NT - 1) stA(aoC, 0, kt + 1, parN); else if (hasN) stA(aoN, 0, 0, parN);
      asm volatile("s_waitcnt lgkmcnt(8)" ::: "memory");
      __builtin_amdgcn_s_barrier();
      LGKM0();
      domfma(0, av);
      __builtin_amdgcn_s_barrier();

      // phase 1
      readA(buf, 1, av);
      if (kt < NT - 1) stA(aoC, 1, kt + 1, parN); else if (hasN) stA(aoN, 1, 0, parN);
      __builtin_amdgcn_s_barrier();
      LGKM0();
      domfma(1, av);
      __builtin_amdgcn_s_barrier();

      // phase 2
      readA(buf, 2, av);
      if (kt < NT - 2) stB(boC, 0, kt + 2, par); else if (hasN) stB(boN, 0, kt + 2 - NT, par);
      __builtin_amdgcn_s_barrier();
      LGKM0();
      domfma(2, av);
      __builtin_amdgcn_s_barrier();

      // phase 3 (tail): counted vmcnt publishes k-tile kt+1
      readA(buf, 3, av);
      if (kt < NT - 2) stB(boC, 1, kt + 2, par); else if (hasN) stB(boN, 1, kt + 2 - NT, par);
      if (hasN || kt < NT - 2)  { asm volatile("s_waitcnt vmcnt(4)" ::: "memory"); }
      else if (kt == NT - 2)    { asm volatile("s_waitcnt vmcnt(0)" ::: "memory"); }
      __builtin_amdgcn_s_barrier();
      LGKM0();
      domfma(3, av);
      __builtin_amdgcn_s_barrier();
    }

    // epilogue for tile cur
    {
      const float* be = bias + (size_t)eC * NCOL;
      int tn = wi & (GX - 1);
      int crow0 = MODE ? tmC * BM : tmrC * BM;
#pragma unroll
      for (int ni = 0; ni < 4; ++ni) {
        int n = tn * 256 + wn * 64 + ni * 16 + lr;
        float bvv = be[n];
#pragma unroll
        for (int mi = 0; mi < 8; ++mi) {
#pragma unroll
          for (int j = 0; j < 4; j++) {
            int mrow = wm * 128 + mi * 16 + kg * 4 + j;   // C/D map m89
            float v = acc[mi][ni][j] + bvv;
            if (MODE == 0) {
              v = fmaxf(v, 0.f);
              ((bf16*)Cout)[(size_t)(crow0 + mrow) * NCOL + n] = __float2bfloat16(v);
            } else {
              ((bf16*)Cout)[(size_t)(crow0 + mrow) * NCOL + n] = __float2bfloat16(v);
            }
          }
        }
      }
    }

    if (!hasN) break;
    wi += GDX;
    aoC[0] = aoN[0]; aoC[1] = aoN[1]; boC[0] = boN[0]; boC[1] = boN[1];
    eC = eN; tmC = tmN; tmrC = tmrN;
    hasN = (wi + GDX) < nW;
    if (hasN) prep(wi + GDX, aoN, boN, eN, tmN, tmrN);
  }
#undef LGKM0
}

// ---- combine (bf16 y) ----
__global__ void k_combine(const bf16* __restrict__ y, const float* __restrict__ prob,
                          const int* __restrict__ pos, float* __restrict__ out) {
  int gid = blockIdx.x * blockDim.x + threadIdx.x;  // over N*D/8
  if (gid >= N_TOK * DDIM / 8) return;
  int n = gid >> 7;          // DDIM/8 = 128
  int d8 = gid & 127;
  int r0 = pos[2 * n], r1 = pos[2 * n + 1];
  float p0 = prob[2 * n], p1 = prob[2 * n + 1];
  uint4 a = *(const uint4*)&y[(size_t)r0 * DDIM + d8 * 8];
  uint4 b = *(const uint4*)&y[(size_t)r1 * DDIM + d8 * 8];
  const unsigned short* ah = (const unsigned short*)&a;
  const unsigned short* bh = (const unsigned short*)&b;
  float o[8];
#pragma unroll
  for (int k = 0; k < 8; k++) {
    float fa = __uint_as_float((unsigned)ah[k] << 16);
    float fb = __uint_as_float((unsigned)bh[k] << 16);
    o[k] = p0 * fa + p1 * fb;
  }
  float4* op = (float4*)&out[(size_t)n * DDIM + d8 * 8];
  op[0] = (float4){o[0], o[1], o[2], o[3]};
  op[1] = (float4){o[4], o[5], o[6], o[7]};
  if (gid == 0) out[(size_t)N_TOK * DDIM] = 0.f;   // total_loss
}

extern "C" void kernel_launch(void* const* d_in, const int* in_sizes, int n_in,
                              void* d_out, int out_size, void* d_ws, size_t ws_size,
                              hipStream_t stream) {
  const float* x    = (const float*)d_in[0];
  const float* prob = (const float*)d_in[1];
  const int*   idx  = (const int*)d_in[2];
  const float* W1   = (const float*)d_in[3];
  const float* b1   = (const float*)d_in[4];
  const float* W2   = (const float*)d_in[5];
  const float* b2   = (const float*)d_in[6];
  float* out = (float*)d_out;

  char* ws = (char*)d_ws;
  size_t cur = 0;
  auto alloc = [&](size_t bytes) -> void* {
    cur = (cur + 255) & ~(size_t)255;
    void* p = ws + cur; cur += bytes; return p;
  };
  int* cnt   = (int*)alloc(NEXP * 4);
  int* offp  = (int*)alloc((NEXP + 1) * 4);
  int* off2  = (int*)alloc(NEXP * 4);
  int* flag  = (int*)alloc(4);
  int* texp  = (int*)alloc(MAXT * 4);
  int* tok   = (int*)alloc((size_t)MAXT * BM * 4);
  int* pos   = (int*)alloc((size_t)NK * 4);
  bf16* Xg   = (bf16*)alloc((size_t)MAXT * BM * DDIM * 2);
  bf16* W1t  = (bf16*)alloc((size_t)NEXP * HDIM * DDIM * 2);
  bf16* W2t  = (bf16*)alloc((size_t)NEXP * DDIM * HDIM * 2);
  bf16* ybuf = (bf16*)alloc((size_t)MAXT * BM * DDIM * 2);
  cur = (cur + 255) & ~(size_t)255;
  size_t h_off = cur;
  size_t h_avail = ws_size > h_off ? ws_size - h_off : 0;
  long long ts_ll = (long long)(h_avail / ((size_t)BM * HDIM * 2));
  int ts = (int)(ts_ll < 1 ? 1 : (ts_ll > MAXT ? MAXT : ts_ll));
  bf16* hbuf = (bf16*)(ws + h_off);

  hipMemsetAsync(cnt, 0, NEXP * 4, stream);
  k_detect<<<1, 64, 0, stream>>>(idx, flag);
  k_count<<<(NK + 255) / 256, 256, 0, stream>>>(idx, flag, cnt);
  k_scan<<<1, 256, 0, stream>>>(cnt, offp, off2, texp, tok);
  k_scatter<<<(NK + 255) / 256, 256, 0, stream>>>(idx, flag, off2, tok, pos);
  k_gather<<<2048, 256, 0, stream>>>(x, tok, offp, Xg);
  k_transpose<<<dim3(HDIM / 32, DDIM / 32, NEXP), 256, 0, stream>>>(W1, W1t, DDIM, HDIM);
  k_transpose<<<dim3(DDIM / 32, HDIM / 32, NEXP), 256, 0, stream>>>(W2, W2t, HDIM, DDIM);

  for (int base = 0; base < MAXT; base += ts) {
    int cnt_t = (MAXT - base < ts) ? (MAXT - base) : ts;
    k_gemm<0><<<256, 512, 0, stream>>>(Xg, W1t, b1, texp, offp, base, cnt_t, (void*)hbuf);
    k_gemm<1><<<256, 512, 0, stream>>>(hbuf, W2t, b2, texp, offp, base, cnt_t, (void*)ybuf);
  }
  k_combine<<<(N_TOK * DDIM / 8 + 255) / 256, 256, 0, stream>>>(ybuf, prob, pos, out);
}